// Round 1
// baseline (1578.582 us; speedup 1.0000x reference)
//
#include <hip/hip_runtime.h>
#include <cfloat>

#define SEQ   2048
#define NE    2048
#define NH    16
#define DIM   128
#define NKV   384
#define QSCALE 0.022097086912079611f  // 1/sqrt(2048) — reference scales by 1/sqrt(N_EMBD)

// ===================== QKV projection =====================
// qkv[h][s][d] = sum_e H[s][e] * Wqkv[h][e][d] + bqkv[h][d]
// d<128 -> q (scaled by QSCALE), 128..255 -> k, 256..383 -> v
// 128x128 tile, BK=16, 256 threads, 8x8 microtile (fp32 vector ALU).
__global__ __launch_bounds__(256) void qkv_kernel(
    const float* __restrict__ H, const float* __restrict__ W,
    const float* __restrict__ bias,
    float* __restrict__ q, float* __restrict__ k, float* __restrict__ v)
{
    const int mt = blockIdx.x, nt = blockIdx.y, h = blockIdx.z;
    const int s0 = mt * 128, n0 = nt * 128;
    const float* Wh = W + (size_t)h * NE * NKV;

    __shared__ float As[16][132];   // A transposed: As[kk][row]
    __shared__ float Bs[16][132];   // Bs[kk][col]

    const int tid = threadIdx.x;
    const int tx = tid & 15, ty = tid >> 4;
    const int a_c4 = tid & 3, a_r = tid >> 2;    // A stage: 4 float4-cols x 64 rows
    const int b_n4 = tid & 31, b_e = tid >> 5;   // B stage: 32 float4-cols x 8 rows

    float acc[8][8];
    #pragma unroll
    for (int i = 0; i < 8; i++)
        #pragma unroll
        for (int j = 0; j < 8; j++) acc[i][j] = 0.f;

    for (int k0 = 0; k0 < NE; k0 += 16) {
        #pragma unroll
        for (int i = 0; i < 2; i++) {
            int r = a_r + 64 * i;
            float4 t = *(const float4*)&H[(size_t)(s0 + r) * NE + k0 + a_c4 * 4];
            As[a_c4 * 4 + 0][r] = t.x;
            As[a_c4 * 4 + 1][r] = t.y;
            As[a_c4 * 4 + 2][r] = t.z;
            As[a_c4 * 4 + 3][r] = t.w;
        }
        #pragma unroll
        for (int i = 0; i < 2; i++) {
            int e = b_e + 8 * i;
            *(float4*)&Bs[e][b_n4 * 4] =
                *(const float4*)&Wh[(size_t)(k0 + e) * NKV + n0 + b_n4 * 4];
        }
        __syncthreads();
        #pragma unroll
        for (int kk = 0; kk < 16; kk++) {
            float4 a0 = *(const float4*)&As[kk][ty * 8];
            float4 a1 = *(const float4*)&As[kk][ty * 8 + 4];
            float4 b0 = *(const float4*)&Bs[kk][tx * 8];
            float4 b1 = *(const float4*)&Bs[kk][tx * 8 + 4];
            float a[8] = {a0.x, a0.y, a0.z, a0.w, a1.x, a1.y, a1.z, a1.w};
            float b[8] = {b0.x, b0.y, b0.z, b0.w, b1.x, b1.y, b1.z, b1.w};
            #pragma unroll
            for (int i = 0; i < 8; i++)
                #pragma unroll
                for (int j = 0; j < 8; j++) acc[i][j] = fmaf(a[i], b[j], acc[i][j]);
        }
        __syncthreads();
    }

    // Tile is 128 wide and n0 is a multiple of 128, so the q/k/v segment is
    // uniform for the whole block (seg = n0/128).
    const int seg = n0 >> 7;
    float* dst = (seg == 0) ? q : ((seg == 1) ? k : v);
    const float mult = (seg == 0) ? QSCALE : 1.f;
    float bv[8];
    #pragma unroll
    for (int j = 0; j < 8; j++) bv[j] = bias[h * NKV + n0 + tx * 8 + j];
    #pragma unroll
    for (int i = 0; i < 8; i++) {
        int s = s0 + ty * 8 + i;
        float* row = dst + ((size_t)h * SEQ + s) * DIM + tx * 8;   // (n0 & 127) == 0
        #pragma unroll
        for (int j = 0; j < 8; j++) row[j] = (acc[i][j] + bv[j]) * mult;
    }
}

// ===================== causal flash attention (fp32) =====================
// One block: head h, 64 query rows. Chunks of 32 keys, online softmax.
__global__ __launch_bounds__(256) void attn_kernel(
    const float* __restrict__ Qm, const float* __restrict__ Km,
    const float* __restrict__ Vm, float* __restrict__ AO)
{
    // reversed so heavy (large qt) blocks dispatch first -> better tail packing
    const int qt = (int)gridDim.x - 1 - (int)blockIdx.x;
    const int h = blockIdx.y;
    const int qs = qt * 64;
    const float* qh = Qm + (size_t)h * SEQ * DIM;
    const float* kh = Km + (size_t)h * SEQ * DIM;
    const float* vh = Vm + (size_t)h * SEQ * DIM;

    __shared__ float Qs[64][132];   // pad 132: 16B-aligned rows, conflict-light
    __shared__ float Ks[32][132];
    __shared__ float Vs[32][128];   // broadcast reads only -> no pad needed
    __shared__ float Ss[64][33];    // pad 33: column reads conflict-free

    const int tid = threadIdx.x;
    const int tx = tid & 15, ty = tid >> 4;   // score phase: 4x2 microtile
    const int sr = tid & 63, sg = tid >> 6;   // softmax/PV phase: row, col-group

    #pragma unroll
    for (int i = 0; i < 8; i++) {
        int f4 = tid + 256 * i;
        int r = f4 >> 5, c4 = f4 & 31;
        *(float4*)&Qs[r][c4 * 4] =
            *(const float4*)&qh[(size_t)(qs + r) * DIM + c4 * 4];
    }

    float m_run = -FLT_MAX, l_run = 0.f;
    float oacc[32];
    #pragma unroll
    for (int j = 0; j < 32; j++) oacc[j] = 0.f;

    for (int t0 = 0; t0 < qs + 64; t0 += 32) {
        __syncthreads();   // previous chunk's readers done before overwrite
        #pragma unroll
        for (int i = 0; i < 4; i++) {
            int f4 = tid + 256 * i;
            int r = f4 >> 5, c4 = f4 & 31;
            *(float4*)&Ks[r][c4 * 4] =
                *(const float4*)&kh[(size_t)(t0 + r) * DIM + c4 * 4];
            *(float4*)&Vs[r][c4 * 4] =
                *(const float4*)&vh[(size_t)(t0 + r) * DIM + c4 * 4];
        }
        __syncthreads();

        // ---- scores: S[64][32] = Qtile . Kchunk^T, 4x2 per thread ----
        float sacc[4][2] = {};
        for (int d4 = 0; d4 < 32; d4++) {
            float4 qv[4], kv[2];
            #pragma unroll
            for (int i = 0; i < 4; i++) qv[i] = *(const float4*)&Qs[ty * 4 + i][d4 * 4];
            #pragma unroll
            for (int j = 0; j < 2; j++) kv[j] = *(const float4*)&Ks[tx * 2 + j][d4 * 4];
            #pragma unroll
            for (int i = 0; i < 4; i++)
                #pragma unroll
                for (int j = 0; j < 2; j++) {
                    sacc[i][j] = fmaf(qv[i].x, kv[j].x, sacc[i][j]);
                    sacc[i][j] = fmaf(qv[i].y, kv[j].y, sacc[i][j]);
                    sacc[i][j] = fmaf(qv[i].z, kv[j].z, sacc[i][j]);
                    sacc[i][j] = fmaf(qv[i].w, kv[j].w, sacc[i][j]);
                }
        }
        #pragma unroll
        for (int i = 0; i < 4; i++)
            #pragma unroll
            for (int j = 0; j < 2; j++) {
                int r = ty * 4 + i, t = tx * 2 + j;
                Ss[r][t] = (t0 + t > qs + r) ? -FLT_MAX : sacc[i][j];
            }
        __syncthreads();

        // ---- online softmax (duplicated across 4 sg-threads per row) + PV ----
        float mc = -FLT_MAX;
        #pragma unroll
        for (int t = 0; t < 32; t++) mc = fmaxf(mc, Ss[sr][t]);
        float m_new = fmaxf(m_run, mc);          // finite after chunk 0 (t=0 always valid)
        float scale = __expf(m_run - m_new);     // first chunk: exp(-huge) = 0
        float p[32], psum = 0.f;
        #pragma unroll
        for (int t = 0; t < 32; t++) {
            p[t] = __expf(Ss[sr][t] - m_new);    // masked: exp(-huge) = 0
            psum += p[t];
        }
        l_run = l_run * scale + psum;
        m_run = m_new;
        #pragma unroll
        for (int j4 = 0; j4 < 8; j4++) {
            float ax = oacc[j4 * 4 + 0] * scale;
            float ay = oacc[j4 * 4 + 1] * scale;
            float az = oacc[j4 * 4 + 2] * scale;
            float aw = oacc[j4 * 4 + 3] * scale;
            #pragma unroll
            for (int t = 0; t < 32; t++) {
                float4 vv = *(const float4*)&Vs[t][sg * 32 + j4 * 4];  // wave-broadcast
                ax = fmaf(p[t], vv.x, ax);
                ay = fmaf(p[t], vv.y, ay);
                az = fmaf(p[t], vv.z, az);
                aw = fmaf(p[t], vv.w, aw);
            }
            oacc[j4 * 4 + 0] = ax; oacc[j4 * 4 + 1] = ay;
            oacc[j4 * 4 + 2] = az; oacc[j4 * 4 + 3] = aw;
        }
    }

    const float inv = 1.f / l_run;   // l_run > 0: chunk 0 has >=1 valid key per row
    #pragma unroll
    for (int j4 = 0; j4 < 8; j4++) {
        float4 o;
        o.x = oacc[j4 * 4 + 0] * inv;
        o.y = oacc[j4 * 4 + 1] * inv;
        o.z = oacc[j4 * 4 + 2] * inv;
        o.w = oacc[j4 * 4 + 3] * inv;
        *(float4*)&AO[(size_t)(qs + sr) * NE + h * DIM + sg * 32 + j4 * 4] = o;
    }
}

// ===================== output projection =====================
// C[2048][2048] = AO . Wout + bout, same 128x128 / BK=16 / 8x8 structure.
__global__ __launch_bounds__(256) void gemm_bias_kernel(
    const float* __restrict__ A, const float* __restrict__ B,
    const float* __restrict__ bias, float* __restrict__ C)
{
    const int mt = blockIdx.x, nt = blockIdx.y;
    const int s0 = mt * 128, n0 = nt * 128;

    __shared__ float As[16][132];
    __shared__ float Bs[16][132];

    const int tid = threadIdx.x;
    const int tx = tid & 15, ty = tid >> 4;
    const int a_c4 = tid & 3, a_r = tid >> 2;
    const int b_n4 = tid & 31, b_e = tid >> 5;

    float acc[8][8];
    #pragma unroll
    for (int i = 0; i < 8; i++)
        #pragma unroll
        for (int j = 0; j < 8; j++) acc[i][j] = 0.f;

    for (int k0 = 0; k0 < NE; k0 += 16) {
        #pragma unroll
        for (int i = 0; i < 2; i++) {
            int r = a_r + 64 * i;
            float4 t = *(const float4*)&A[(size_t)(s0 + r) * NE + k0 + a_c4 * 4];
            As[a_c4 * 4 + 0][r] = t.x;
            As[a_c4 * 4 + 1][r] = t.y;
            As[a_c4 * 4 + 2][r] = t.z;
            As[a_c4 * 4 + 3][r] = t.w;
        }
        #pragma unroll
        for (int i = 0; i < 2; i++) {
            int e = b_e + 8 * i;
            *(float4*)&Bs[e][b_n4 * 4] =
                *(const float4*)&B[(size_t)(k0 + e) * NE + n0 + b_n4 * 4];
        }
        __syncthreads();
        #pragma unroll
        for (int kk = 0; kk < 16; kk++) {
            float4 a0 = *(const float4*)&As[kk][ty * 8];
            float4 a1 = *(const float4*)&As[kk][ty * 8 + 4];
            float4 b0 = *(const float4*)&Bs[kk][tx * 8];
            float4 b1 = *(const float4*)&Bs[kk][tx * 8 + 4];
            float a[8] = {a0.x, a0.y, a0.z, a0.w, a1.x, a1.y, a1.z, a1.w};
            float b[8] = {b0.x, b0.y, b0.z, b0.w, b1.x, b1.y, b1.z, b1.w};
            #pragma unroll
            for (int i = 0; i < 8; i++)
                #pragma unroll
                for (int j = 0; j < 8; j++) acc[i][j] = fmaf(a[i], b[j], acc[i][j]);
        }
        __syncthreads();
    }

    float bv[8];
    #pragma unroll
    for (int j = 0; j < 8; j++) bv[j] = bias[n0 + tx * 8 + j];
    #pragma unroll
    for (int i = 0; i < 8; i++) {
        float* row = C + (size_t)(s0 + ty * 8 + i) * NE + n0 + tx * 8;
        float4 o0, o1;
        o0.x = acc[i][0] + bv[0]; o0.y = acc[i][1] + bv[1];
        o0.z = acc[i][2] + bv[2]; o0.w = acc[i][3] + bv[3];
        o1.x = acc[i][4] + bv[4]; o1.y = acc[i][5] + bv[5];
        o1.z = acc[i][6] + bv[6]; o1.w = acc[i][7] + bv[7];
        *(float4*)&row[0] = o0;
        *(float4*)&row[4] = o1;
    }
}

extern "C" void kernel_launch(void* const* d_in, const int* in_sizes, int n_in,
                              void* d_out, int out_size, void* d_ws, size_t ws_size,
                              hipStream_t stream) {
    const float* H    = (const float*)d_in[0];   // [2048][2048]
    const float* Wqkv = (const float*)d_in[1];   // [16][2048][384]
    const float* bqkv = (const float*)d_in[2];   // [16][384]
    const float* Wout = (const float*)d_in[3];   // [2048][2048]
    const float* bout = (const float*)d_in[4];   // [2048]
    float* out = (float*)d_out;                  // [2048][2048]

    float* ws = (float*)d_ws;
    const size_t HSD = (size_t)NH * SEQ * DIM;   // 4,194,304 floats = 16 MB
    float* q  = ws;                              // [16][2048][128], pre-scaled
    float* k  = ws + HSD;
    float* v  = ws + 2 * HSD;
    float* AO = ws + 3 * HSD;                    // [2048][2048] (s-major, h*128+d)

    qkv_kernel<<<dim3(SEQ / 128, NKV / 128, NH), 256, 0, stream>>>(
        H, Wqkv, bqkv, q, k, v);
    attn_kernel<<<dim3(SEQ / 64, NH), 256, 0, stream>>>(q, k, v, AO);
    gemm_bias_kernel<<<dim3(SEQ / 128, NE / 128), 256, 0, stream>>>(
        AO, Wout, bout, out);
}

// Round 3
// 722.285 us; speedup vs baseline: 2.1855x; 2.1855x over previous
//
#include <hip/hip_runtime.h>
#include <cfloat>

#define SEQ   2048
#define NE    2048
#define NH    16
#define DIM   128
#define NKV   384
#define QSCALE 0.022097086912079611f  // 1/sqrt(2048)

typedef __attribute__((ext_vector_type(8))) short bf16x8;      // MFMA A/B frag (4 VGPR)
typedef __attribute__((ext_vector_type(4))) float f32x4;       // MFMA C/D frag
typedef __attribute__((ext_vector_type(8))) unsigned short u16x8;

__device__ __forceinline__ unsigned short f32_to_bf16_rn(float x) {
    unsigned u = __builtin_bit_cast(unsigned, x);
    u += 0x7fffu + ((u >> 16) & 1u);          // round-to-nearest-even
    return (unsigned short)(u >> 16);
}

__device__ __forceinline__ void gload16(const void* g, void* l) {
    __builtin_amdgcn_global_load_lds(
        (const __attribute__((address_space(1))) unsigned int*)g,
        (__attribute__((address_space(3))) unsigned int*)l, 16, 0, 0);
}

// ============ convert fp32 -> bf16 (elementwise) ============
__global__ __launch_bounds__(256) void convert_bf16_kernel(
    const float* __restrict__ src, unsigned short* __restrict__ dst, int n4)
{
    for (int i = blockIdx.x * 256 + threadIdx.x; i < n4; i += gridDim.x * 256) {
        float4 x = ((const float4*)src)[i];
        ushort4 h;
        h.x = f32_to_bf16_rn(x.x);
        h.y = f32_to_bf16_rn(x.y);
        h.z = f32_to_bf16_rn(x.z);
        h.w = f32_to_bf16_rn(x.w);
        ((ushort4*)dst)[i] = h;
    }
}

// ====== transpose-convert: src[b][K][N] fp32 -> dst[b][N][K] bf16 ======
// 64x64 tiles. Load: 1024 float4 (4 iters). Write: 512 u16x8 (2 iters — the
// round-2 bug was 4 iters here, writing rows 64..127 out of tile range).
__global__ __launch_bounds__(256) void transpose_bf16_kernel(
    const float* __restrict__ src, unsigned short* __restrict__ dst, int K, int N)
{
    const int kt = blockIdx.x, nt = blockIdx.y, b = blockIdx.z;
    const float* s = src + (size_t)b * K * N;
    __shared__ float tile[64][65];
    const int tid = threadIdx.x;
    #pragma unroll
    for (int i = 0; i < 4; i++) {
        int idx = tid + 256 * i;                 // 0..1023: 64 rows x 16 float4
        int kk = idx >> 4, n4 = idx & 15;
        float4 val = *(const float4*)&s[(size_t)(kt * 64 + kk) * N + nt * 64 + n4 * 4];
        tile[kk][n4 * 4 + 0] = val.x; tile[kk][n4 * 4 + 1] = val.y;
        tile[kk][n4 * 4 + 2] = val.z; tile[kk][n4 * 4 + 3] = val.w;
    }
    __syncthreads();
    #pragma unroll
    for (int i = 0; i < 2; i++) {
        int idx = tid + 256 * i;                 // 0..511: 64 rows x 8 chunks
        int nn = idx >> 3, k8 = idx & 7;
        u16x8 hv;
        #pragma unroll
        for (int j = 0; j < 8; j++)
            hv[j] = f32_to_bf16_rn(tile[k8 * 8 + j][nn]);
        size_t off = ((size_t)b * N + nt * 64 + nn) * K + kt * 64 + k8 * 8;
        *(u16x8*)&dst[off] = hv;
    }
}

// ============ bf16 MFMA GEMM ============
// C[m][n] = sum_k A[m][k]*B[k][n]; A bf16 [M][K] (k-contig), B bf16 [N][K]
// (k-contig, pre-transposed). 128x128 tile, BK=64, 4 waves (2x2 of 64x64),
// mfma_f32_16x16x32_bf16. LDS linear [plane][128][64]; XOR swizzle
// (slot ^ row&7) applied to per-lane GLOBAL source (global_load_lds writes
// linearly: G21 both-sides-or-neither) and to the ds_read address.
// EPI 0: qkv (z = head; bias bqkv, scatter q/k/v, q pre-scaled)
// EPI 1: out-proj (bias bout, fp32 out)
template<int EPI>
__global__ __launch_bounds__(256, 2) void gemm_bf16_kernel(
    const unsigned short* __restrict__ A, const unsigned short* __restrict__ B,
    const float* __restrict__ bias,
    float* __restrict__ o0, float* __restrict__ o1, float* __restrict__ o2)
{
    __shared__ unsigned short smem[2][128][64];   // A, B planes: 32 KiB
    const int tid = threadIdx.x;
    const int wave = tid >> 6, lane = tid & 63;
    const int s0 = blockIdx.x * 128, n0 = blockIdx.y * 128, z = blockIdx.z;
    const int bRowBase = (EPI == 0) ? (z * NKV + n0) : n0;

    // staging: wave w stages rows w*32..w*32+31 per plane (4 issues x 8 rows)
    const int srow = lane >> 3;                       // row within 8-row group
    const int sswz = ((lane & 7) ^ srow) << 4;        // pre-swizzled byte slot
    size_t aoff[4], boff[4];
    #pragma unroll
    for (int j = 0; j < 4; j++) {
        int ra = s0 + wave * 32 + j * 8 + srow;
        int rb = bRowBase + wave * 32 + j * 8 + srow;
        aoff[j] = 2 * ((size_t)ra * NE) + sswz;
        boff[j] = 2 * ((size_t)rb * NE) + sswz;
    }
    const char* pA = (const char*)A;
    const char* pB = (const char*)B;

    f32x4 acc[4][4];
    #pragma unroll
    for (int i = 0; i < 4; i++)
        #pragma unroll
        for (int j = 0; j < 4; j++) acc[i][j] = (f32x4){0.f, 0.f, 0.f, 0.f};

    const int wm = wave >> 1, wn = wave & 1;
    const int fr = lane & 15, kg = lane >> 4;

    for (int k0 = 0; k0 < NE; k0 += 64) {
        #pragma unroll
        for (int j = 0; j < 4; j++) {
            gload16(pA + aoff[j], &smem[0][wave * 32 + j * 8][0]);
            gload16(pB + boff[j], &smem[1][wave * 32 + j * 8][0]);
            aoff[j] += 128; boff[j] += 128;
        }
        __syncthreads();

        #pragma unroll
        for (int kh = 0; kh < 2; kh++) {
            bf16x8 af[4], bf[4];
            #pragma unroll
            for (int f = 0; f < 4; f++) {
                int ra = wm * 64 + f * 16 + fr;
                int ca = ((kh * 4 + kg) ^ (ra & 7)) << 4;
                af[f] = *(const bf16x8*)((const char*)&smem[0][0][0] + ra * 128 + ca);
                int rb = wn * 64 + f * 16 + fr;
                int cb = ((kh * 4 + kg) ^ (rb & 7)) << 4;
                bf[f] = *(const bf16x8*)((const char*)&smem[1][0][0] + rb * 128 + cb);
            }
            #pragma unroll
            for (int fm = 0; fm < 4; fm++)
                #pragma unroll
                for (int fn = 0; fn < 4; fn++)
                    acc[fm][fn] = __builtin_amdgcn_mfma_f32_16x16x32_bf16(
                        af[fm], bf[fn], acc[fm][fn], 0, 0, 0);
        }
        __syncthreads();
    }

    // epilogue: C/D layout col=lane&15, row=(lane>>4)*4+reg (m89-verified)
    #pragma unroll
    for (int fm = 0; fm < 4; fm++)
        #pragma unroll
        for (int fn = 0; fn < 4; fn++) {
            int col = wn * 64 + fn * 16 + fr;
            int row = wm * 64 + fm * 16 + kg * 4;
            if (EPI == 0) {
                const int seg = n0 >> 7;              // tile-uniform: 0=q 1=k 2=v
                float* dst = (seg == 0) ? o0 : ((seg == 1) ? o1 : o2);
                const float mult = (seg == 0) ? QSCALE : 1.f;
                float bv = bias[z * NKV + n0 + col];
                #pragma unroll
                for (int r = 0; r < 4; r++)
                    dst[((size_t)(z * SEQ + s0 + row + r)) * DIM + col] =
                        (acc[fm][fn][r] + bv) * mult;
            } else {
                float bv = bias[n0 + col];
                #pragma unroll
                for (int r = 0; r < 4; r++)
                    o0[((size_t)(s0 + row + r)) * NE + n0 + col] = acc[fm][fn][r] + bv;
            }
        }
}

// ===================== causal flash attention (fp32) =====================
// Unchanged compute; epilogue emits AO as bf16 for the out-proj GEMM.
__global__ __launch_bounds__(256) void attn_kernel(
    const float* __restrict__ Qm, const float* __restrict__ Km,
    const float* __restrict__ Vm, unsigned short* __restrict__ AOb)
{
    const int qt = (int)gridDim.x - 1 - (int)blockIdx.x;
    const int h = blockIdx.y;
    const int qs = qt * 64;
    const float* qh = Qm + (size_t)h * SEQ * DIM;
    const float* kh = Km + (size_t)h * SEQ * DIM;
    const float* vh = Vm + (size_t)h * SEQ * DIM;

    __shared__ float Qs[64][132];
    __shared__ float Ks[32][132];
    __shared__ float Vs[32][128];
    __shared__ float Ss[64][33];

    const int tid = threadIdx.x;
    const int tx = tid & 15, ty = tid >> 4;
    const int sr = tid & 63, sg = tid >> 6;

    #pragma unroll
    for (int i = 0; i < 8; i++) {
        int f4 = tid + 256 * i;
        int r = f4 >> 5, c4 = f4 & 31;
        *(float4*)&Qs[r][c4 * 4] = *(const float4*)&qh[(size_t)(qs + r) * DIM + c4 * 4];
    }

    float m_run = -FLT_MAX, l_run = 0.f;
    float oacc[32];
    #pragma unroll
    for (int j = 0; j < 32; j++) oacc[j] = 0.f;

    for (int t0 = 0; t0 < qs + 64; t0 += 32) {
        __syncthreads();
        #pragma unroll
        for (int i = 0; i < 4; i++) {
            int f4 = tid + 256 * i;
            int r = f4 >> 5, c4 = f4 & 31;
            *(float4*)&Ks[r][c4 * 4] = *(const float4*)&kh[(size_t)(t0 + r) * DIM + c4 * 4];
            *(float4*)&Vs[r][c4 * 4] = *(const float4*)&vh[(size_t)(t0 + r) * DIM + c4 * 4];
        }
        __syncthreads();

        float sacc[4][2] = {};
        for (int d4 = 0; d4 < 32; d4++) {
            float4 qv[4], kv[2];
            #pragma unroll
            for (int i = 0; i < 4; i++) qv[i] = *(const float4*)&Qs[ty * 4 + i][d4 * 4];
            #pragma unroll
            for (int j = 0; j < 2; j++) kv[j] = *(const float4*)&Ks[tx * 2 + j][d4 * 4];
            #pragma unroll
            for (int i = 0; i < 4; i++)
                #pragma unroll
                for (int j = 0; j < 2; j++) {
                    sacc[i][j] = fmaf(qv[i].x, kv[j].x, sacc[i][j]);
                    sacc[i][j] = fmaf(qv[i].y, kv[j].y, sacc[i][j]);
                    sacc[i][j] = fmaf(qv[i].z, kv[j].z, sacc[i][j]);
                    sacc[i][j] = fmaf(qv[i].w, kv[j].w, sacc[i][j]);
                }
        }
        #pragma unroll
        for (int i = 0; i < 4; i++)
            #pragma unroll
            for (int j = 0; j < 2; j++) {
                int r = ty * 4 + i, t = tx * 2 + j;
                Ss[r][t] = (t0 + t > qs + r) ? -FLT_MAX : sacc[i][j];
            }
        __syncthreads();

        float mc = -FLT_MAX;
        #pragma unroll
        for (int t = 0; t < 32; t++) mc = fmaxf(mc, Ss[sr][t]);
        float m_new = fmaxf(m_run, mc);
        float scale = __expf(m_run - m_new);
        float p[32], psum = 0.f;
        #pragma unroll
        for (int t = 0; t < 32; t++) {
            p[t] = __expf(Ss[sr][t] - m_new);
            psum += p[t];
        }
        l_run = l_run * scale + psum;
        m_run = m_new;
        #pragma unroll
        for (int j4 = 0; j4 < 8; j4++) {
            float ax = oacc[j4 * 4 + 0] * scale;
            float ay = oacc[j4 * 4 + 1] * scale;
            float az = oacc[j4 * 4 + 2] * scale;
            float aw = oacc[j4 * 4 + 3] * scale;
            #pragma unroll
            for (int t = 0; t < 32; t++) {
                float4 vv = *(const float4*)&Vs[t][sg * 32 + j4 * 4];
                ax = fmaf(p[t], vv.x, ax);
                ay = fmaf(p[t], vv.y, ay);
                az = fmaf(p[t], vv.z, az);
                aw = fmaf(p[t], vv.w, aw);
            }
            oacc[j4 * 4 + 0] = ax; oacc[j4 * 4 + 1] = ay;
            oacc[j4 * 4 + 2] = az; oacc[j4 * 4 + 3] = aw;
        }
    }

    const float inv = 1.f / l_run;
    #pragma unroll
    for (int j4 = 0; j4 < 8; j4++) {
        ushort4 hv;
        hv.x = f32_to_bf16_rn(oacc[j4 * 4 + 0] * inv);
        hv.y = f32_to_bf16_rn(oacc[j4 * 4 + 1] * inv);
        hv.z = f32_to_bf16_rn(oacc[j4 * 4 + 2] * inv);
        hv.w = f32_to_bf16_rn(oacc[j4 * 4 + 3] * inv);
        *(ushort4*)&AOb[(size_t)(qs + sr) * NE + h * DIM + sg * 32 + j4 * 4] = hv;
    }
}

extern "C" void kernel_launch(void* const* d_in, const int* in_sizes, int n_in,
                              void* d_out, int out_size, void* d_ws, size_t ws_size,
                              hipStream_t stream) {
    const float* H    = (const float*)d_in[0];   // [2048][2048]
    const float* Wqkv = (const float*)d_in[1];   // [16][2048][384]
    const float* bqkv = (const float*)d_in[2];   // [16][384]
    const float* Wout = (const float*)d_in[3];   // [2048][2048]
    const float* bout = (const float*)d_in[4];   // [2048]
    float* out = (float*)d_out;

    char* W8 = (char*)d_ws;
    const size_t MiB = 1ull << 20;
    float* q  = (float*)(W8 + 0);                       // [16][2048][128] fp32, q pre-scaled
    float* k  = (float*)(W8 + 16 * MiB);
    float* v  = (float*)(W8 + 32 * MiB);
    unsigned short* Hb  = (unsigned short*)(W8 + 48 * MiB);   // [2048][2048] bf16
    unsigned short* AOb = (unsigned short*)(W8 + 56 * MiB);   // [2048][2048] bf16
    unsigned short* Wob = (unsigned short*)(W8 + 64 * MiB);   // [2048][2048] bf16 (n-major)
    unsigned short* Wqb = (unsigned short*)(W8 + 72 * MiB);   // [16][384][2048] bf16 -> 96 MiB

    convert_bf16_kernel<<<1024, 256, 0, stream>>>(H, Hb, SEQ * NE / 4);
    transpose_bf16_kernel<<<dim3(NE / 64, NKV / 64, NH), 256, 0, stream>>>(
        Wqkv, Wqb, NE, NKV);
    transpose_bf16_kernel<<<dim3(NE / 64, NE / 64, 1), 256, 0, stream>>>(
        Wout, Wob, NE, NE);
    gemm_bf16_kernel<0><<<dim3(SEQ / 128, NKV / 128, NH), 256, 0, stream>>>(
        Hb, Wqb, bqkv, q, k, v);
    attn_kernel<<<dim3(SEQ / 64, NH), 256, 0, stream>>>(q, k, v, AOb);
    gemm_bf16_kernel<1><<<dim3(SEQ / 128, NE / 128, 1), 256, 0, stream>>>(
        AOb, Wob, bout, out, nullptr, nullptr);
}

// Round 4
// 207.886 us; speedup vs baseline: 7.5935x; 3.4744x over previous
//
#include <hip/hip_runtime.h>
#include <cfloat>

#define SEQ   2048
#define NE    2048
#define NH    16
#define DIM   128
#define NKV   384
#define QSCALE 0.022097086912079611f  // 1/sqrt(2048)

typedef __attribute__((ext_vector_type(8))) short bf16x8;      // MFMA A/B frag (4 VGPR)
typedef __attribute__((ext_vector_type(4))) float f32x4;       // MFMA C/D frag
typedef __attribute__((ext_vector_type(8))) unsigned short u16x8;

__device__ __forceinline__ unsigned short f32_to_bf16_rn(float x) {
    unsigned u = __builtin_bit_cast(unsigned, x);
    u += 0x7fffu + ((u >> 16) & 1u);          // round-to-nearest-even
    return (unsigned short)(u >> 16);
}

__device__ __forceinline__ void gload16(const void* g, void* l) {
    __builtin_amdgcn_global_load_lds(
        (const __attribute__((address_space(1))) unsigned int*)g,
        (__attribute__((address_space(3))) unsigned int*)l, 16, 0, 0);
}

// ============ convert fp32 -> bf16 (elementwise) ============
__global__ __launch_bounds__(256) void convert_bf16_kernel(
    const float* __restrict__ src, unsigned short* __restrict__ dst, int n4)
{
    for (int i = blockIdx.x * 256 + threadIdx.x; i < n4; i += gridDim.x * 256) {
        float4 x = ((const float4*)src)[i];
        ushort4 h;
        h.x = f32_to_bf16_rn(x.x);
        h.y = f32_to_bf16_rn(x.y);
        h.z = f32_to_bf16_rn(x.z);
        h.w = f32_to_bf16_rn(x.w);
        ((ushort4*)dst)[i] = h;
    }
}

// ====== transpose-convert: src[b][K][N] fp32 -> dst[b][N][K] bf16 ======
__global__ __launch_bounds__(256) void transpose_bf16_kernel(
    const float* __restrict__ src, unsigned short* __restrict__ dst, int K, int N)
{
    const int kt = blockIdx.x, nt = blockIdx.y, b = blockIdx.z;
    const float* s = src + (size_t)b * K * N;
    __shared__ float tile[64][65];
    const int tid = threadIdx.x;
    #pragma unroll
    for (int i = 0; i < 4; i++) {
        int idx = tid + 256 * i;                 // 0..1023: 64 rows x 16 float4
        int kk = idx >> 4, n4 = idx & 15;
        float4 val = *(const float4*)&s[(size_t)(kt * 64 + kk) * N + nt * 64 + n4 * 4];
        tile[kk][n4 * 4 + 0] = val.x; tile[kk][n4 * 4 + 1] = val.y;
        tile[kk][n4 * 4 + 2] = val.z; tile[kk][n4 * 4 + 3] = val.w;
    }
    __syncthreads();
    #pragma unroll
    for (int i = 0; i < 2; i++) {
        int idx = tid + 256 * i;                 // 0..511: 64 rows x 8 chunks
        int nn = idx >> 3, k8 = idx & 7;
        u16x8 hv;
        #pragma unroll
        for (int j = 0; j < 8; j++)
            hv[j] = f32_to_bf16_rn(tile[k8 * 8 + j][nn]);
        size_t off = ((size_t)b * N + nt * 64 + nn) * K + kt * 64 + k8 * 8;
        *(u16x8*)&dst[off] = hv;
    }
}

// ============ bf16 MFMA GEMM (unchanged structure from round 3) ============
// EPI 0: qkv -> bf16 q (pre-scaled), k, v   EPI 1: out-proj -> fp32 out
template<int EPI>
__global__ __launch_bounds__(256, 2) void gemm_bf16_kernel(
    const unsigned short* __restrict__ A, const unsigned short* __restrict__ B,
    const float* __restrict__ bias, void* o0v, void* o1v, void* o2v)
{
    __shared__ unsigned short smem[2][128][64];   // A, B planes: 32 KiB
    const int tid = threadIdx.x;
    const int wave = tid >> 6, lane = tid & 63;
    const int s0 = blockIdx.x * 128, n0 = blockIdx.y * 128, z = blockIdx.z;
    const int bRowBase = (EPI == 0) ? (z * NKV + n0) : n0;

    const int srow = lane >> 3;
    const int sswz = ((lane & 7) ^ srow) << 4;
    size_t aoff[4], boff[4];
    #pragma unroll
    for (int j = 0; j < 4; j++) {
        int ra = s0 + wave * 32 + j * 8 + srow;
        int rb = bRowBase + wave * 32 + j * 8 + srow;
        aoff[j] = 2 * ((size_t)ra * NE) + sswz;
        boff[j] = 2 * ((size_t)rb * NE) + sswz;
    }
    const char* pA = (const char*)A;
    const char* pB = (const char*)B;

    f32x4 acc[4][4];
    #pragma unroll
    for (int i = 0; i < 4; i++)
        #pragma unroll
        for (int j = 0; j < 4; j++) acc[i][j] = (f32x4){0.f, 0.f, 0.f, 0.f};

    const int wm = wave >> 1, wn = wave & 1;
    const int fr = lane & 15, kg = lane >> 4;

    for (int k0 = 0; k0 < NE; k0 += 64) {
        #pragma unroll
        for (int j = 0; j < 4; j++) {
            gload16(pA + aoff[j], &smem[0][wave * 32 + j * 8][0]);
            gload16(pB + boff[j], &smem[1][wave * 32 + j * 8][0]);
            aoff[j] += 128; boff[j] += 128;
        }
        __syncthreads();

        #pragma unroll
        for (int kh = 0; kh < 2; kh++) {
            bf16x8 af[4], bf[4];
            #pragma unroll
            for (int f = 0; f < 4; f++) {
                int ra = wm * 64 + f * 16 + fr;
                int ca = ((kh * 4 + kg) ^ (ra & 7)) << 4;
                af[f] = *(const bf16x8*)((const char*)&smem[0][0][0] + ra * 128 + ca);
                int rb = wn * 64 + f * 16 + fr;
                int cb = ((kh * 4 + kg) ^ (rb & 7)) << 4;
                bf[f] = *(const bf16x8*)((const char*)&smem[1][0][0] + rb * 128 + cb);
            }
            #pragma unroll
            for (int fm = 0; fm < 4; fm++)
                #pragma unroll
                for (int fn = 0; fn < 4; fn++)
                    acc[fm][fn] = __builtin_amdgcn_mfma_f32_16x16x32_bf16(
                        af[fm], bf[fn], acc[fm][fn], 0, 0, 0);
        }
        __syncthreads();
    }

    #pragma unroll
    for (int fm = 0; fm < 4; fm++)
        #pragma unroll
        for (int fn = 0; fn < 4; fn++) {
            int col = wn * 64 + fn * 16 + fr;
            int row = wm * 64 + fm * 16 + kg * 4;
            if (EPI == 0) {
                const int seg = n0 >> 7;              // tile-uniform: 0=q 1=k 2=v
                unsigned short* dst = (seg == 0) ? (unsigned short*)o0v
                                   : ((seg == 1) ? (unsigned short*)o1v
                                                 : (unsigned short*)o2v);
                const float mult = (seg == 0) ? QSCALE : 1.f;
                float bv = bias[z * NKV + n0 + col];
                #pragma unroll
                for (int r = 0; r < 4; r++)
                    dst[((size_t)(z * SEQ + s0 + row + r)) * DIM + col] =
                        f32_to_bf16_rn((acc[fm][fn][r] + bv) * mult);
            } else {
                float* out = (float*)o0v;
                float bv = bias[n0 + col];
                #pragma unroll
                for (int r = 0; r < 4; r++)
                    out[((size_t)(s0 + row + r)) * NE + n0 + col] = acc[fm][fn][r] + bv;
            }
        }
}

// ===================== causal flash attention, bf16 MFMA =====================
// 4 waves/block; wave w owns 16 q-rows (Q0 = qs + w*16). KVBLK = 64.
// QK^T: A = Q (regs), B = K (LDS, G21 XOR-swizzle). C layout (m89):
// col = lane&15 = key, row = (lane>>4)*4 + r = q-row.
// Softmax: per-r shfl_xor(1,2,4,8) reduce within 16-lane groups.
// PV: P via per-wave LDS tile (A-frag), V transposed in LDS (B-frag).
__global__ __launch_bounds__(256, 3) void attn_mfma_kernel(
    const unsigned short* __restrict__ Qb, const unsigned short* __restrict__ Kb,
    const unsigned short* __restrict__ Vb, unsigned short* __restrict__ AOb)
{
    const int qt = (int)gridDim.x - 1 - (int)blockIdx.x;   // heavy tiles first
    const int h = blockIdx.y;
    const int qs = qt * 64;
    const char* kh = (const char*)(Kb + (size_t)h * SEQ * DIM);
    const unsigned short* vh = Vb + (size_t)h * SEQ * DIM;

    __shared__ __align__(16) unsigned short Klds[64 * 128];   // swizzled rows, 256 B each
    __shared__ __align__(16) unsigned short Vt[128][88];      // V^T [dim][key], pad 88
    __shared__ __align__(16) unsigned short Plds[4][16][88];  // per-wave P tile

    const int tid = threadIdx.x;
    const int w = tid >> 6, lane = tid & 63;
    const int fr = lane & 15, g = lane >> 4;
    const int Q0 = qs + w * 16;

    // Q A-frags: lane holds Q[Q0+fr][kc*32 + g*8 .. +7], 4 chunks of 32 dims
    bf16x8 qf[4];
    {
        const unsigned short* qrow = Qb + ((size_t)h * SEQ + Q0 + fr) * DIM;
        #pragma unroll
        for (int kc = 0; kc < 4; kc++)
            qf[kc] = *(const bf16x8*)&qrow[kc * 32 + g * 8];
    }

    // V staging assignment: 2 keys x 16 dims per thread
    const int key0 = (tid & 31) * 2;
    const int dbase = (tid >> 5) * 16;

    f32x4 oacc[8];
    #pragma unroll
    for (int d = 0; d < 8; d++) oacc[d] = (f32x4){0.f, 0.f, 0.f, 0.f};
    float m_run[4], l_run[4];
    #pragma unroll
    for (int r = 0; r < 4; r++) { m_run[r] = -FLT_MAX; l_run[r] = 0.f; }

    const int nkv = qs / 64 + 1;
    for (int it = 0; it < nkv; ++it) {
        const int t0 = it * 64;
        __syncthreads();                          // everyone done with prev K/Vt
        // ---- stage K: 64 rows x 256 B, pre-swizzled source, linear LDS dest ----
        #pragma unroll
        for (int j = 0; j < 4; j++) {
            int row = w * 16 + j * 4 + g;         // this lane's dest row
            gload16(kh + (size_t)(t0 + row) * 256 + ((fr ^ (row & 7)) << 4),
                    &Klds[(w * 16 + j * 4) * 128]);
        }
        // ---- stage V transposed: thread loads 2 keys x 16 dims, packs u32 ----
        {
            const u16x8* r0 = (const u16x8*)&vh[(size_t)(t0 + key0) * DIM + dbase];
            const u16x8* r1 = (const u16x8*)&vh[(size_t)(t0 + key0 + 1) * DIM + dbase];
            u16x8 a0 = r0[0], a1 = r0[1], b0 = r1[0], b1 = r1[1];
            #pragma unroll
            for (int j = 0; j < 8; j++) {
                *(unsigned*)&Vt[dbase + j][key0]     = (unsigned)a0[j] | ((unsigned)b0[j] << 16);
                *(unsigned*)&Vt[dbase + 8 + j][key0] = (unsigned)a1[j] | ((unsigned)b1[j] << 16);
            }
        }
        __syncthreads();                          // K + Vt visible

        // ---- QK^T: S[16 q][64 keys], 4 n-tiles x 4 k-chunks ----
        f32x4 sacc[4];
        #pragma unroll
        for (int nt = 0; nt < 4; nt++) sacc[nt] = (f32x4){0.f, 0.f, 0.f, 0.f};
        #pragma unroll
        for (int nt = 0; nt < 4; nt++) {
            int rk = nt * 16 + fr;
            #pragma unroll
            for (int kc = 0; kc < 4; kc++) {
                bf16x8 kf = *(const bf16x8*)((const char*)Klds +
                                rk * 256 + (((kc * 4 + g) ^ (rk & 7)) << 4));
                sacc[nt] = __builtin_amdgcn_mfma_f32_16x16x32_bf16(
                    qf[kc], kf, sacc[nt], 0, 0, 0);
            }
        }

        // ---- causal mask (only on the wave's partial/diagonal tile) ----
        const bool partial = (t0 + 63 > Q0);      // wave-uniform
        if (partial) {
            #pragma unroll
            for (int nt = 0; nt < 4; nt++) {
                int key = t0 + nt * 16 + fr;
                #pragma unroll
                for (int r = 0; r < 4; r++) {
                    int q = Q0 + g * 4 + r;
                    sacc[nt][r] = (key > q) ? -3.0e38f : sacc[nt][r];
                }
            }
        }

        // ---- online softmax ----
        float mnew[4], sc[4];
        #pragma unroll
        for (int r = 0; r < 4; r++) {
            float mx = fmaxf(fmaxf(sacc[0][r], sacc[1][r]),
                             fmaxf(sacc[2][r], sacc[3][r]));
            mx = fmaxf(mx, __shfl_xor(mx, 1));
            mx = fmaxf(mx, __shfl_xor(mx, 2));
            mx = fmaxf(mx, __shfl_xor(mx, 4));
            mx = fmaxf(mx, __shfl_xor(mx, 8));
            mnew[r] = fmaxf(m_run[r], mx);
            sc[r] = __expf(m_run[r] - mnew[r]);
            m_run[r] = mnew[r];
        }
        float ps[4] = {0.f, 0.f, 0.f, 0.f};
        #pragma unroll
        for (int nt = 0; nt < 4; nt++)
            #pragma unroll
            for (int r = 0; r < 4; r++) {
                float p = __expf(sacc[nt][r] - mnew[r]);
                sacc[nt][r] = p;
                ps[r] += p;
            }
        #pragma unroll
        for (int r = 0; r < 4; r++) {
            float s = ps[r];
            s += __shfl_xor(s, 1);
            s += __shfl_xor(s, 2);
            s += __shfl_xor(s, 4);
            s += __shfl_xor(s, 8);
            l_run[r] = l_run[r] * sc[r] + s;
        }
        // rescale O
        #pragma unroll
        for (int d = 0; d < 8; d++)
            #pragma unroll
            for (int r = 0; r < 4; r++) oacc[d][r] *= sc[r];

        // ---- P -> per-wave LDS (bf16, C-layout scatter) ----
        #pragma unroll
        for (int nt = 0; nt < 4; nt++)
            #pragma unroll
            for (int r = 0; r < 4; r++)
                Plds[w][g * 4 + r][nt * 16 + fr] = f32_to_bf16_rn(sacc[nt][r]);

        // ---- PV: O += P[16][64] . V[64][128] ----
        #pragma unroll
        for (int c = 0; c < 2; c++) {
            if (partial && (t0 + c * 32 > Q0 + 15)) continue;   // fully masked chunk
            bf16x8 pf = *(const bf16x8*)&Plds[w][fr][c * 32 + g * 8];
            #pragma unroll
            for (int dt = 0; dt < 8; dt++) {
                bf16x8 vf = *(const bf16x8*)&Vt[dt * 16 + fr][c * 32 + g * 8];
                oacc[dt] = __builtin_amdgcn_mfma_f32_16x16x32_bf16(
                    pf, vf, oacc[dt], 0, 0, 0);
            }
        }
    }

    // ---- epilogue: O / l -> bf16 AO[s][h*128+d] ----
    float inv[4];
    #pragma unroll
    for (int r = 0; r < 4; r++) inv[r] = 1.f / l_run[r];
    #pragma unroll
    for (int dt = 0; dt < 8; dt++)
        #pragma unroll
        for (int r = 0; r < 4; r++)
            AOb[(size_t)(Q0 + g * 4 + r) * NE + h * DIM + dt * 16 + fr] =
                f32_to_bf16_rn(oacc[dt][r] * inv[r]);
}

extern "C" void kernel_launch(void* const* d_in, const int* in_sizes, int n_in,
                              void* d_out, int out_size, void* d_ws, size_t ws_size,
                              hipStream_t stream) {
    const float* H    = (const float*)d_in[0];   // [2048][2048]
    const float* Wqkv = (const float*)d_in[1];   // [16][2048][384]
    const float* bqkv = (const float*)d_in[2];   // [16][384]
    const float* Wout = (const float*)d_in[3];   // [2048][2048]
    const float* bout = (const float*)d_in[4];   // [2048]
    float* out = (float*)d_out;

    char* W8 = (char*)d_ws;
    const size_t MiB = 1ull << 20;
    unsigned short* qb  = (unsigned short*)(W8 + 0);         // [16][2048][128] bf16 (pre-scaled)
    unsigned short* kb  = (unsigned short*)(W8 + 8 * MiB);   // [16][2048][128] bf16
    unsigned short* vb  = (unsigned short*)(W8 + 16 * MiB);  // [16][2048][128] bf16
    unsigned short* Hb  = (unsigned short*)(W8 + 24 * MiB);  // [2048][2048] bf16
    unsigned short* AOb = (unsigned short*)(W8 + 32 * MiB);  // [2048][2048] bf16
    unsigned short* Wob = (unsigned short*)(W8 + 40 * MiB);  // [2048][2048] bf16 (n-major)
    unsigned short* Wqb = (unsigned short*)(W8 + 48 * MiB);  // [16][384][2048] bf16 -> 72 MiB

    convert_bf16_kernel<<<1024, 256, 0, stream>>>(H, Hb, SEQ * NE / 4);
    transpose_bf16_kernel<<<dim3(NE / 64, NKV / 64, NH), 256, 0, stream>>>(
        Wqkv, Wqb, NE, NKV);
    transpose_bf16_kernel<<<dim3(NE / 64, NE / 64, 1), 256, 0, stream>>>(
        Wout, Wob, NE, NE);
    gemm_bf16_kernel<0><<<dim3(SEQ / 128, NKV / 128, NH), 256, 0, stream>>>(
        Hb, Wqb, bqkv, qb, kb, vb);
    attn_mfma_kernel<<<dim3(SEQ / 64, NH), 256, 0, stream>>>(qb, kb, vb, AOb);
    gemm_bf16_kernel<1><<<dim3(SEQ / 128, NE / 128, 1), 256, 0, stream>>>(
        AOb, Wob, bout, out, nullptr, nullptr);
}

// Round 5
// 188.447 us; speedup vs baseline: 8.3768x; 1.1032x over previous
//
#include <hip/hip_runtime.h>
#include <cfloat>

#define SEQ   2048
#define NE    2048
#define NH    16
#define DIM   128
#define NKV   384
#define QSCALE 0.022097086912079611f  // 1/sqrt(2048)

typedef __attribute__((ext_vector_type(8))) short bf16x8;      // MFMA A/B frag (4 VGPR)
typedef __attribute__((ext_vector_type(4))) float f32x4;       // MFMA C/D frag
typedef __attribute__((ext_vector_type(8))) unsigned short u16x8;

__device__ __forceinline__ unsigned short f32_to_bf16_rn(float x) {
    unsigned u = __builtin_bit_cast(unsigned, x);
    u += 0x7fffu + ((u >> 16) & 1u);          // round-to-nearest-even
    return (unsigned short)(u >> 16);
}

__device__ __forceinline__ void gload16(const void* g, void* l) {
    __builtin_amdgcn_global_load_lds(
        (const __attribute__((address_space(1))) unsigned int*)g,
        (__attribute__((address_space(3))) unsigned int*)l, 16, 0, 0);
}

// ============ convert fp32 -> bf16 (elementwise) ============
__global__ __launch_bounds__(256) void convert_bf16_kernel(
    const float* __restrict__ src, unsigned short* __restrict__ dst, int n4)
{
    for (int i = blockIdx.x * 256 + threadIdx.x; i < n4; i += gridDim.x * 256) {
        float4 x = ((const float4*)src)[i];
        ushort4 h;
        h.x = f32_to_bf16_rn(x.x);
        h.y = f32_to_bf16_rn(x.y);
        h.z = f32_to_bf16_rn(x.z);
        h.w = f32_to_bf16_rn(x.w);
        ((ushort4*)dst)[i] = h;
    }
}

// ====== transpose-convert: src[b][K][N] fp32 -> dst[b][N][K] bf16 ======
__global__ __launch_bounds__(256) void transpose_bf16_kernel(
    const float* __restrict__ src, unsigned short* __restrict__ dst, int K, int N)
{
    const int kt = blockIdx.x, nt = blockIdx.y, b = blockIdx.z;
    const float* s = src + (size_t)b * K * N;
    __shared__ float tile[64][65];
    const int tid = threadIdx.x;
    #pragma unroll
    for (int i = 0; i < 4; i++) {
        int idx = tid + 256 * i;                 // 0..1023: 64 rows x 16 float4
        int kk = idx >> 4, n4 = idx & 15;
        float4 val = *(const float4*)&s[(size_t)(kt * 64 + kk) * N + nt * 64 + n4 * 4];
        tile[kk][n4 * 4 + 0] = val.x; tile[kk][n4 * 4 + 1] = val.y;
        tile[kk][n4 * 4 + 2] = val.z; tile[kk][n4 * 4 + 3] = val.w;
    }
    __syncthreads();
    #pragma unroll
    for (int i = 0; i < 2; i++) {
        int idx = tid + 256 * i;                 // 0..511: 64 rows x 8 chunks
        int nn = idx >> 3, k8 = idx & 7;
        u16x8 hv;
        #pragma unroll
        for (int j = 0; j < 8; j++)
            hv[j] = f32_to_bf16_rn(tile[k8 * 8 + j][nn]);
        size_t off = ((size_t)b * N + nt * 64 + nn) * K + kt * 64 + k8 * 8;
        *(u16x8*)&dst[off] = hv;
    }
}

// ============ bf16 MFMA GEMM (unchanged from round 4) ============
template<int EPI>
__global__ __launch_bounds__(256, 2) void gemm_bf16_kernel(
    const unsigned short* __restrict__ A, const unsigned short* __restrict__ B,
    const float* __restrict__ bias, void* o0v, void* o1v, void* o2v)
{
    __shared__ unsigned short smem[2][128][64];   // A, B planes: 32 KiB
    const int tid = threadIdx.x;
    const int wave = tid >> 6, lane = tid & 63;
    const int s0 = blockIdx.x * 128, n0 = blockIdx.y * 128, z = blockIdx.z;
    const int bRowBase = (EPI == 0) ? (z * NKV + n0) : n0;

    const int srow = lane >> 3;
    const int sswz = ((lane & 7) ^ srow) << 4;
    size_t aoff[4], boff[4];
    #pragma unroll
    for (int j = 0; j < 4; j++) {
        int ra = s0 + wave * 32 + j * 8 + srow;
        int rb = bRowBase + wave * 32 + j * 8 + srow;
        aoff[j] = 2 * ((size_t)ra * NE) + sswz;
        boff[j] = 2 * ((size_t)rb * NE) + sswz;
    }
    const char* pA = (const char*)A;
    const char* pB = (const char*)B;

    f32x4 acc[4][4];
    #pragma unroll
    for (int i = 0; i < 4; i++)
        #pragma unroll
        for (int j = 0; j < 4; j++) acc[i][j] = (f32x4){0.f, 0.f, 0.f, 0.f};

    const int wm = wave >> 1, wn = wave & 1;
    const int fr = lane & 15, kg = lane >> 4;

    for (int k0 = 0; k0 < NE; k0 += 64) {
        #pragma unroll
        for (int j = 0; j < 4; j++) {
            gload16(pA + aoff[j], &smem[0][wave * 32 + j * 8][0]);
            gload16(pB + boff[j], &smem[1][wave * 32 + j * 8][0]);
            aoff[j] += 128; boff[j] += 128;
        }
        __syncthreads();

        #pragma unroll
        for (int kh = 0; kh < 2; kh++) {
            bf16x8 af[4], bf[4];
            #pragma unroll
            for (int f = 0; f < 4; f++) {
                int ra = wm * 64 + f * 16 + fr;
                int ca = ((kh * 4 + kg) ^ (ra & 7)) << 4;
                af[f] = *(const bf16x8*)((const char*)&smem[0][0][0] + ra * 128 + ca);
                int rb = wn * 64 + f * 16 + fr;
                int cb = ((kh * 4 + kg) ^ (rb & 7)) << 4;
                bf[f] = *(const bf16x8*)((const char*)&smem[1][0][0] + rb * 128 + cb);
            }
            #pragma unroll
            for (int fm = 0; fm < 4; fm++)
                #pragma unroll
                for (int fn = 0; fn < 4; fn++)
                    acc[fm][fn] = __builtin_amdgcn_mfma_f32_16x16x32_bf16(
                        af[fm], bf[fn], acc[fm][fn], 0, 0, 0);
        }
        __syncthreads();
    }

    #pragma unroll
    for (int fm = 0; fm < 4; fm++)
        #pragma unroll
        for (int fn = 0; fn < 4; fn++) {
            int col = wn * 64 + fn * 16 + fr;
            int row = wm * 64 + fm * 16 + kg * 4;
            if (EPI == 0) {
                const int seg = n0 >> 7;              // tile-uniform: 0=q 1=k 2=v
                unsigned short* dst = (seg == 0) ? (unsigned short*)o0v
                                   : ((seg == 1) ? (unsigned short*)o1v
                                                 : (unsigned short*)o2v);
                const float mult = (seg == 0) ? QSCALE : 1.f;
                float bv = bias[z * NKV + n0 + col];
                #pragma unroll
                for (int r = 0; r < 4; r++)
                    dst[((size_t)(z * SEQ + s0 + row + r)) * DIM + col] =
                        f32_to_bf16_rn((acc[fm][fn][r] + bv) * mult);
            } else {
                float* out = (float*)o0v;
                float bv = bias[n0 + col];
                #pragma unroll
                for (int r = 0; r < 4; r++)
                    out[((size_t)(s0 + row + r)) * NE + n0 + col] = acc[fm][fn][r] + bv;
            }
        }
}

// ===================== causal flash attention, bf16 MFMA v2 =====================
// 1D grid 512. Complementary-pair remap: lin<256 -> qt=lin&31, h=lin>>5;
// lin>=256 -> qt=31-(lin&31), h=8+((lin&255)>>5). If dispatch round-robins
// CUs, each CU's two blocks sum to 33 KV-tiles -> balanced makespan.
// Double-buffered K (global_load_lds) + Vt (reg-staged transpose); ONE barrier
// per tile; prefetch of tile t+1 issued before compute of t (T14).
// Pads: 72 shorts (144 B rows) -> 16 B-aligned b128 reads, uniform bank load.
__global__ __launch_bounds__(256, 2) void attn_mfma_kernel(
    const unsigned short* __restrict__ Qb, const unsigned short* __restrict__ Kb,
    const unsigned short* __restrict__ Vb, unsigned short* __restrict__ AOb)
{
    const int lin = (int)blockIdx.x;
    const int halfg = lin >> 8;
    const int idx = lin & 255;
    const int qt = halfg ? (31 - (idx & 31)) : (idx & 31);
    const int h = (halfg << 3) + (idx >> 5);

    const char* kh = (const char*)(Kb + (size_t)h * SEQ * DIM);
    const unsigned short* vh = Vb + (size_t)h * SEQ * DIM;

    __shared__ __align__(16) unsigned short Klds[2][64 * 128];  // 2 x 16 KiB
    __shared__ __align__(16) unsigned short Vt[2][128][72];     // 2 x 18 KiB
    __shared__ __align__(16) unsigned short Plds[4][16][72];    // 9 KiB

    const int tid = threadIdx.x;
    const int w = tid >> 6, lane = tid & 63;
    const int fr = lane & 15, g = lane >> 4;
    const int qs = qt * 64;
    const int Q0 = qs + w * 16;

    // Q A-frags: lane holds Q[Q0+fr][kc*32 + g*8 .. +7]
    bf16x8 qf[4];
    {
        const unsigned short* qrow = Qb + ((size_t)h * SEQ + Q0 + fr) * DIM;
        #pragma unroll
        for (int kc = 0; kc < 4; kc++)
            qf[kc] = *(const bf16x8*)&qrow[kc * 32 + g * 8];
    }

    const int key0 = (tid & 31) * 2;          // V staging: 2 keys x 16 dims/thread
    const int dbase = (tid >> 5) * 16;

    f32x4 oacc[8];
    #pragma unroll
    for (int d = 0; d < 8; d++) oacc[d] = (f32x4){0.f, 0.f, 0.f, 0.f};
    float m_run[4], l_run[4];
    #pragma unroll
    for (int r = 0; r < 4; r++) { m_run[r] = -FLT_MAX; l_run[r] = 0.f; }

    const int nt = qt + 1;
    u16x8 va0, va1, vc0, vc1;                 // V prefetch registers

    // ---- prologue: stage tile 0 into buf 0 ----
    #pragma unroll
    for (int j = 0; j < 4; j++) {
        int row = w * 16 + j * 4 + g;
        gload16(kh + (size_t)row * 256 + ((fr ^ (row & 7)) << 4),
                &Klds[0][(w * 16 + j * 4) * 128]);
    }
    {
        const u16x8* r0 = (const u16x8*)&vh[(size_t)key0 * DIM + dbase];
        const u16x8* r1 = (const u16x8*)&vh[(size_t)(key0 + 1) * DIM + dbase];
        va0 = r0[0]; va1 = r0[1]; vc0 = r1[0]; vc1 = r1[1];
    }
    #pragma unroll
    for (int j = 0; j < 8; j++) {
        *(unsigned*)&Vt[0][dbase + j][key0]     = (unsigned)(unsigned short)va0[j] | ((unsigned)(unsigned short)vc0[j] << 16);
        *(unsigned*)&Vt[0][dbase + 8 + j][key0] = (unsigned)(unsigned short)va1[j] | ((unsigned)(unsigned short)vc1[j] << 16);
    }
    asm volatile("s_waitcnt vmcnt(0)" ::: "memory");

    for (int t = 0; t < nt; t++) {
        __syncthreads();                      // buf[t&1] K+Vt visible to all
        const int buf = t & 1;
        const int t0 = t * 64;
        const bool last = (t == qt);          // wave-uniform

        // ---- prefetch tile t+1: K -> LDS[buf^1] (async), V -> regs ----
        if (!last) {
            const int t1 = t0 + 64;
            #pragma unroll
            for (int j = 0; j < 4; j++) {
                int row = w * 16 + j * 4 + g;
                gload16(kh + (size_t)(t1 + row) * 256 + ((fr ^ (row & 7)) << 4),
                        &Klds[buf ^ 1][(w * 16 + j * 4) * 128]);
            }
            const u16x8* r0 = (const u16x8*)&vh[(size_t)(t1 + key0) * DIM + dbase];
            const u16x8* r1 = (const u16x8*)&vh[(size_t)(t1 + key0 + 1) * DIM + dbase];
            va0 = r0[0]; va1 = r0[1]; vc0 = r1[0]; vc1 = r1[1];
        }

        // ---- QK^T: S[16 q][64 keys] ----
        f32x4 sacc[4];
        #pragma unroll
        for (int n4 = 0; n4 < 4; n4++) sacc[n4] = (f32x4){0.f, 0.f, 0.f, 0.f};
        #pragma unroll
        for (int n4 = 0; n4 < 4; n4++) {
            int rk = n4 * 16 + fr;
            #pragma unroll
            for (int kc = 0; kc < 4; kc++) {
                bf16x8 kf = *(const bf16x8*)((const char*)&Klds[buf][0] +
                                rk * 256 + (((kc * 4 + g) ^ (rk & 7)) << 4));
                sacc[n4] = __builtin_amdgcn_mfma_f32_16x16x32_bf16(
                    qf[kc], kf, sacc[n4], 0, 0, 0);
            }
        }

        // ---- causal mask (diagonal tile only) ----
        if (last) {
            #pragma unroll
            for (int n4 = 0; n4 < 4; n4++) {
                int key = t0 + n4 * 16 + fr;
                #pragma unroll
                for (int r = 0; r < 4; r++) {
                    int q = Q0 + g * 4 + r;
                    sacc[n4][r] = (key > q) ? -3.0e38f : sacc[n4][r];
                }
            }
        }

        // ---- online softmax ----
        float mnew[4], sc[4];
        #pragma unroll
        for (int r = 0; r < 4; r++) {
            float mx = fmaxf(fmaxf(sacc[0][r], sacc[1][r]),
                             fmaxf(sacc[2][r], sacc[3][r]));
            mx = fmaxf(mx, __shfl_xor(mx, 1));
            mx = fmaxf(mx, __shfl_xor(mx, 2));
            mx = fmaxf(mx, __shfl_xor(mx, 4));
            mx = fmaxf(mx, __shfl_xor(mx, 8));
            mnew[r] = fmaxf(m_run[r], mx);
            sc[r] = __expf(m_run[r] - mnew[r]);
            m_run[r] = mnew[r];
        }
        float ps[4] = {0.f, 0.f, 0.f, 0.f};
        #pragma unroll
        for (int n4 = 0; n4 < 4; n4++)
            #pragma unroll
            for (int r = 0; r < 4; r++) {
                float p = __expf(sacc[n4][r] - mnew[r]);
                sacc[n4][r] = p;
                ps[r] += p;
            }
        #pragma unroll
        for (int r = 0; r < 4; r++) {
            float s = ps[r];
            s += __shfl_xor(s, 1);
            s += __shfl_xor(s, 2);
            s += __shfl_xor(s, 4);
            s += __shfl_xor(s, 8);
            l_run[r] = l_run[r] * sc[r] + s;
        }
        #pragma unroll
        for (int d = 0; d < 8; d++)
            #pragma unroll
            for (int r = 0; r < 4; r++) oacc[d][r] *= sc[r];

        // ---- P -> per-wave LDS (in-wave ordering, no barrier) ----
        #pragma unroll
        for (int n4 = 0; n4 < 4; n4++)
            #pragma unroll
            for (int r = 0; r < 4; r++)
                Plds[w][g * 4 + r][n4 * 16 + fr] = f32_to_bf16_rn(sacc[n4][r]);

        // ---- PV: O += P[16][64] . V[64][128] ----
        #pragma unroll
        for (int c = 0; c < 2; c++) {
            if (last && (t0 + c * 32 > Q0 + 15)) continue;   // fully-masked chunk
            bf16x8 pf = *(const bf16x8*)&Plds[w][fr][c * 32 + g * 8];
            #pragma unroll
            for (int dt = 0; dt < 8; dt++) {
                bf16x8 vf = *(const bf16x8*)&Vt[buf][dt * 16 + fr][c * 32 + g * 8];
                oacc[dt] = __builtin_amdgcn_mfma_f32_16x16x32_bf16(
                    pf, vf, oacc[dt], 0, 0, 0);
            }
        }

        // ---- late half of prefetch: write Vt[buf^1], drain K gloads ----
        if (!last) {
            #pragma unroll
            for (int j = 0; j < 8; j++) {
                *(unsigned*)&Vt[buf ^ 1][dbase + j][key0]     = (unsigned)(unsigned short)va0[j] | ((unsigned)(unsigned short)vc0[j] << 16);
                *(unsigned*)&Vt[buf ^ 1][dbase + 8 + j][key0] = (unsigned)(unsigned short)va1[j] | ((unsigned)(unsigned short)vc1[j] << 16);
            }
            asm volatile("s_waitcnt vmcnt(0)" ::: "memory");
        }
    }

    // ---- epilogue: O / l -> bf16 AO[s][h*128+d] ----
    float inv[4];
    #pragma unroll
    for (int r = 0; r < 4; r++) inv[r] = 1.f / l_run[r];
    #pragma unroll
    for (int dt = 0; dt < 8; dt++)
        #pragma unroll
        for (int r = 0; r < 4; r++)
            AOb[(size_t)(Q0 + g * 4 + r) * NE + h * DIM + dt * 16 + fr] =
                f32_to_bf16_rn(oacc[dt][r] * inv[r]);
}

extern "C" void kernel_launch(void* const* d_in, const int* in_sizes, int n_in,
                              void* d_out, int out_size, void* d_ws, size_t ws_size,
                              hipStream_t stream) {
    const float* H    = (const float*)d_in[0];   // [2048][2048]
    const float* Wqkv = (const float*)d_in[1];   // [16][2048][384]
    const float* bqkv = (const float*)d_in[2];   // [16][384]
    const float* Wout = (const float*)d_in[3];   // [2048][2048]
    const float* bout = (const float*)d_in[4];   // [2048]
    float* out = (float*)d_out;

    char* W8 = (char*)d_ws;
    const size_t MiB = 1ull << 20;
    unsigned short* qb  = (unsigned short*)(W8 + 0);         // [16][2048][128] bf16 (pre-scaled)
    unsigned short* kb  = (unsigned short*)(W8 + 8 * MiB);   // [16][2048][128] bf16
    unsigned short* vb  = (unsigned short*)(W8 + 16 * MiB);  // [16][2048][128] bf16
    unsigned short* Hb  = (unsigned short*)(W8 + 24 * MiB);  // [2048][2048] bf16
    unsigned short* AOb = (unsigned short*)(W8 + 32 * MiB);  // [2048][2048] bf16
    unsigned short* Wob = (unsigned short*)(W8 + 40 * MiB);  // [2048][2048] bf16 (n-major)
    unsigned short* Wqb = (unsigned short*)(W8 + 48 * MiB);  // [16][384][2048] bf16 -> 72 MiB

    convert_bf16_kernel<<<1024, 256, 0, stream>>>(H, Hb, SEQ * NE / 4);
    transpose_bf16_kernel<<<dim3(NE / 64, NKV / 64, NH), 256, 0, stream>>>(
        Wqkv, Wqb, NE, NKV);
    transpose_bf16_kernel<<<dim3(NE / 64, NE / 64, 1), 256, 0, stream>>>(
        Wout, Wob, NE, NE);
    gemm_bf16_kernel<0><<<dim3(SEQ / 128, NKV / 128, NH), 256, 0, stream>>>(
        Hb, Wqb, bqkv, qb, kb, vb);
    attn_mfma_kernel<<<dim3(512), 256, 0, stream>>>(qb, kb, vb, AOb);
    gemm_bf16_kernel<1><<<dim3(SEQ / 128, NE / 128, 1), 256, 0, stream>>>(
        AOb, Wob, bout, out, nullptr, nullptr);
}